// Round 4
// baseline (5064.938 us; speedup 1.0000x reference)
//
#include <hip/hip_runtime.h>

// Problem dims
#define V_ 50257
#define E_ 512
#define H_ 1024
#define LM_ 128
#define LC_ 256
#define NBLK 64   // blocks in persistent recurrence kernels

typedef __attribute__((ext_vector_type(8))) short short8;
typedef __attribute__((ext_vector_type(4))) float f32x4;
typedef unsigned long long u64;

__device__ __forceinline__ unsigned short f2bf(float x) {
  union { float f; unsigned u; } v; v.f = x;
  unsigned r = v.u + 0x7fffu + ((v.u >> 16) & 1u);   // round-to-nearest-even
  return (unsigned short)(r >> 16);
}
__device__ __forceinline__ float bflo(unsigned u) { union { unsigned u; float f; } v; v.u = u << 16; return v.f; }
__device__ __forceinline__ float bfhi(unsigned u) { union { unsigned u; float f; } v; v.u = u & 0xffff0000u; return v.f; }

__device__ __forceinline__ int grow_map(int s, int i0) {
  return (s < 16) ? (i0 + s) : (s < 32) ? (1024 + i0 + (s - 16)) : (2048 + i0 + (s - 32));
}

// relaxed agent-scope packet ops (cache-bypassing, NO fences -> no L2 flush/inv)
__device__ __forceinline__ void pub_pk(u64* p, unsigned gen, unsigned payload) {
  __hip_atomic_store(p, ((u64)gen << 32) | (u64)payload, __ATOMIC_RELAXED, __HIP_MEMORY_SCOPE_AGENT);
}
__device__ __forceinline__ u64 ld_pk(const u64* p) {
  return __hip_atomic_load(p, __ATOMIC_RELAXED, __HIP_MEMORY_SCOPE_AGENT);
}
__device__ __forceinline__ unsigned ld_flag(const unsigned* p) {
  return __hip_atomic_load(p, __ATOMIC_RELAXED, __HIP_MEMORY_SCOPE_AGENT);
}
__device__ __forceinline__ void st_flag(unsigned* p, unsigned v) {
  __hip_atomic_store(p, v, __ATOMIC_RELAXED, __HIP_MEMORY_SCOPE_AGENT);
}

// wave-0 flag wait: lane b polls publisher b's flag line until all >= need.
// 1 load per line per block per round; ~430 ns sleep quantum.
__device__ __forceinline__ void wait_flags(const unsigned* flags, unsigned need, int tid) {
  if (tid < 64) {
    for (;;) {
      unsigned f = ld_flag(&flags[tid * 16]);
      if (__all(f >= need)) break;
      __builtin_amdgcn_s_sleep(16);
    }
  }
  __syncthreads();
}

// ---------------- gathers ----------------
__global__ void gather_enc(const int* __restrict__ motion, const float* __restrict__ emb,
                           float* __restrict__ dst) {
  int t = blockIdx.x;
  int tok = motion[t];
  const float4* s = (const float4*)(emb + (size_t)tok * E_);
  float4* d = (float4*)(dst + (size_t)t * E_);
  d[threadIdx.x] = s[threadIdx.x];
}

__global__ void gather_dec(const int* __restrict__ tgt, const float* __restrict__ emb,
                           float* __restrict__ dst) {
  int t = blockIdx.x;
  int tok = (t == 0) ? 0 : (t == 1 ? tgt[LC_ - 1] : tgt[t - 2]);
  const float4* s = (const float4*)(emb + (size_t)tok * H_);
  float4* d = (float4*)(dst + (size_t)t * H_);
  d[threadIdx.x] = s[threadIdx.x];
}

// ---------------- generic f32 GEMM: C[M,N] = A[M,K](lda) @ B[N,K](ldb)^T + bias ----------------
__global__ __launch_bounds__(256) void gemm_f32(const float* __restrict__ A, int lda,
                                                const float* __restrict__ B, int ldb,
                                                const float* __restrict__ bias,
                                                float* __restrict__ C, int ldc, int K) {
  __shared__ float As[16][68];
  __shared__ float Bs[16][68];
  const int bm = blockIdx.y * 64, bn = blockIdx.x * 64;
  const int tid = threadIdx.x;
  const int tx = tid & 15, ty = tid >> 4;
  const int lm = tid & 63, lk = (tid >> 6) * 4;
  float acc[4][4] = {};
  for (int k0 = 0; k0 < K; k0 += 16) {
    float4 av = *(const float4*)&A[(size_t)(bm + lm) * lda + k0 + lk];
    float4 bv = *(const float4*)&B[(size_t)(bn + lm) * ldb + k0 + lk];
    As[lk + 0][lm] = av.x; As[lk + 1][lm] = av.y; As[lk + 2][lm] = av.z; As[lk + 3][lm] = av.w;
    Bs[lk + 0][lm] = bv.x; Bs[lk + 1][lm] = bv.y; Bs[lk + 2][lm] = bv.z; Bs[lk + 3][lm] = bv.w;
    __syncthreads();
#pragma unroll
    for (int kk = 0; kk < 16; ++kk) {
      float4 a4 = *(const float4*)&As[kk][ty * 4];
      float4 b4 = *(const float4*)&Bs[kk][tx * 4];
      acc[0][0] += a4.x * b4.x; acc[0][1] += a4.x * b4.y; acc[0][2] += a4.x * b4.z; acc[0][3] += a4.x * b4.w;
      acc[1][0] += a4.y * b4.x; acc[1][1] += a4.y * b4.y; acc[1][2] += a4.y * b4.z; acc[1][3] += a4.y * b4.w;
      acc[2][0] += a4.z * b4.x; acc[2][1] += a4.z * b4.y; acc[2][2] += a4.z * b4.z; acc[2][3] += a4.z * b4.w;
      acc[3][0] += a4.w * b4.x; acc[3][1] += a4.w * b4.y; acc[3][2] += a4.w * b4.z; acc[3][3] += a4.w * b4.w;
    }
    __syncthreads();
  }
#pragma unroll
  for (int i = 0; i < 4; ++i) {
#pragma unroll
    for (int j = 0; j < 4; ++j) {
      int gm = bm + ty * 4 + i, gn = bn + tx * 4 + j;
      float bv = bias ? bias[gn] : 0.f;
      C[(size_t)gm * ldc + gn] = acc[i][j] + bv;
    }
  }
}

// ---------------- encoder recurrence: 64 blocks x 256 threads, flag-gated burst exchange ----
// hx = [2][512] u64 packets {gen:u32, 2xbf16}. step t consumes gen t (slot t&1), publishes
// gen t+1 (slot (t+1)&1). eflags[b*16] = latest gen published by block b.
__global__ __launch_bounds__(256) void enc_rnn(const float* __restrict__ Whh,
                                               const float* __restrict__ bhh,
                                               const float* __restrict__ gi,
                                               u64* __restrict__ hx,
                                               unsigned* __restrict__ eflags,
                                               float* __restrict__ outs) {
  __shared__ unsigned short Whl[48][1024];
  __shared__ unsigned h_sh[512];   // bf16-pair packed h
  __shared__ float h_own[16];
  __shared__ float bh[48];
  __shared__ float ghl[48];
  const int b = blockIdx.x, tid = threadIdx.x;
  const int w = tid >> 6, l = tid & 63;
  const int i0 = b * 16;
  for (int idx = tid; idx < 48 * 1024; idx += 256) {
    int s = idx >> 10, c = idx & 1023;
    Whl[s][c] = f2bf(Whh[(size_t)grow_map(s, i0) * H_ + c]);
  }
  if (tid < 48) bh[tid] = bhh[grow_map(tid, i0)];
  if (tid < 16) h_own[tid] = 0.f;
  __syncthreads();

  for (int t = 0; t < LM_; ++t) {
    if (t == 0) {
      h_sh[2 * tid] = 0u; h_sh[2 * tid + 1] = 0u;
    } else {
      wait_flags(eflags, (unsigned)t, tid);
      const u64* base = hx + (t & 1) * 512;
      u64 p0 = ld_pk(base + 2 * tid);
      u64 p1 = ld_pk(base + 2 * tid + 1);
      while ((unsigned)(p0 >> 32) != (unsigned)t || (unsigned)(p1 >> 32) != (unsigned)t) {
        __builtin_amdgcn_s_sleep(8);
        p0 = ld_pk(base + 2 * tid); p1 = ld_pk(base + 2 * tid + 1);
      }
      h_sh[2 * tid] = (unsigned)p0;
      h_sh[2 * tid + 1] = (unsigned)p1;
    }
    __syncthreads();

    for (int s = w; s < 48; s += 4) {
      float acc = 0.f;
#pragma unroll
      for (int e = 0; e < 8; ++e) {
        unsigned u = *(const unsigned*)&Whl[s][2 * (e * 64 + l)];
        unsigned hv = h_sh[e * 64 + l];
        acc += bflo(u) * bflo(hv) + bfhi(u) * bfhi(hv);
      }
#pragma unroll
      for (int off = 32; off; off >>= 1) acc += __shfl_xor(acc, off);
      if (l == 0) ghl[s] = acc;
    }
    __syncthreads();
    if (tid < 16) {
      int i = tid, ig = i0 + i;
      const float* git = gi + (size_t)t * 3072;
      float gr = git[ig], gz = git[1024 + ig], gn = git[2048 + ig];
      float hr = ghl[i] + bh[i], hz = ghl[16 + i] + bh[16 + i], hn = ghl[32 + i] + bh[32 + i];
      float r = 1.f / (1.f + expf(-(gr + hr)));
      float z = 1.f / (1.f + expf(-(gz + hz)));
      float n = tanhf(gn + r * hn);
      float hpv = (1.f - z) * n + z * h_own[i];
      h_own[i] = hpv;
      outs[(size_t)t * H_ + ig] = hpv;
      float v0 = __shfl(hpv, (tid & 7) * 2);
      float v1 = __shfl(hpv, (tid & 7) * 2 + 1);
      if (tid < 8) {
        unsigned payload = (unsigned)f2bf(v0) | ((unsigned)f2bf(v1) << 16);
        pub_pk(&hx[((t + 1) & 1) * 512 + b * 8 + tid], (unsigned)(t + 1), payload);
      }
    }
    __syncthreads();  // drains wave-0's data stores (vmcnt) + protects h_sh/ghl
    if (tid == 0) st_flag(&eflags[b * 16], (unsigned)(t + 1));
  }
}

// ---------------- decoder recurrence: 64 blocks x 256 threads, flag-gated burst exchange ----
// h gens continue from encoder (g = 128+t). a_pk single-slot [128] {gen, f32}.
// dflags[b*16]: 2t+1 after block b's a-publish of step t; 2t+2 after its h-publish.
__global__ __launch_bounds__(256) void dec_rnn(const float* __restrict__ Whh,
                                               const float* __restrict__ bhh,
                                               const float* __restrict__ attn_W,
                                               const float* __restrict__ G,
                                               const float* __restrict__ P1,
                                               const float* __restrict__ aE,
                                               const float* __restrict__ hfin,
                                               u64* __restrict__ a_pk,
                                               u64* __restrict__ hx,
                                               unsigned* __restrict__ dflags,
                                               unsigned short* __restrict__ Hs) {
  __shared__ unsigned short Whl[48][1024];  // 96 KB
  __shared__ float Al[2][1024];             // 8 KB
  __shared__ float Gl[48][128];             // 24 KB
  __shared__ unsigned h_sh[512];            // 2 KB
  __shared__ float af[128];
  __shared__ float h_own[16];
  __shared__ float bh[48];
  __shared__ float ghl[48];
  __shared__ float giS[48];
  const int b = blockIdx.x, tid = threadIdx.x;
  const int w = tid >> 6, l = tid & 63;
  const int i0 = b * 16;
  for (int idx = tid; idx < 48 * 1024; idx += 256) {
    int s = idx >> 10, c = idx & 1023;
    Whl[s][c] = f2bf(Whh[(size_t)grow_map(s, i0) * H_ + c]);
  }
  for (int idx = tid; idx < 2 * 1024; idx += 256) {
    int j = idx >> 10, c = idx & 1023;
    Al[j][c] = attn_W[(size_t)(2 * b + j) * 2048 + 1024 + c];
  }
  for (int idx = tid; idx < 48 * 128; idx += 256) {
    int s = idx >> 7, c = idx & 127;
    Gl[s][c] = G[(size_t)grow_map(s, i0) * 128 + c];
  }
  if (tid < 48) bh[tid] = bhh[grow_map(tid, i0)];
  if (tid < 16) h_own[tid] = hfin[i0 + tid];   // exact f32 encoder-final h
  __syncthreads();

  for (int t = 0; t < LC_; ++t) {
    const unsigned g = (unsigned)(LM_ + t);
    // ---- h arrival (step t>0: previous step's h-publish flags; t==0: pre-launch data) ----
    if (t) wait_flags(dflags, (unsigned)(2 * t), tid);
    {
      const u64* base = hx + (g & 1) * 512;
      u64 p0 = ld_pk(base + 2 * tid);
      u64 p1 = ld_pk(base + 2 * tid + 1);
      while ((unsigned)(p0 >> 32) != g || (unsigned)(p1 >> 32) != g) {
        __builtin_amdgcn_s_sleep(8);
        p0 = ld_pk(base + 2 * tid); p1 = ld_pk(base + 2 * tid + 1);
      }
      h_sh[2 * tid] = (unsigned)p0;
      h_sh[2 * tid + 1] = (unsigned)p1;
    }
    __syncthreads();

    // phase A: 48 Whh rows + 2 attn rows (a published with embedded gen t+1)
    for (int s = w; s < 50; s += 4) {
      float acc = 0.f;
      if (s < 48) {
#pragma unroll
        for (int e = 0; e < 8; ++e) {
          unsigned u = *(const unsigned*)&Whl[s][2 * (e * 64 + l)];
          unsigned hv = h_sh[e * 64 + l];
          acc += bflo(u) * bflo(hv) + bfhi(u) * bfhi(hv);
        }
      } else {
        const float* ar = Al[s - 48];
#pragma unroll
        for (int e = 0; e < 8; ++e) {
          float2 av = *(const float2*)&ar[2 * (e * 64 + l)];
          unsigned hv = h_sh[e * 64 + l];
          acc += av.x * bflo(hv) + av.y * bfhi(hv);
        }
      }
#pragma unroll
      for (int off = 32; off; off >>= 1) acc += __shfl_xor(acc, off);
      if (l == 0) {
        if (s < 48) ghl[s] = acc;
        else {
          float av = acc + aE[(size_t)t * LM_ + 2 * b + (s - 48)];
          pub_pk(&a_pk[2 * b + (s - 48)], (unsigned)(t + 1), __float_as_uint(av));
        }
      }
    }
    __syncthreads();  // drains a-publisher waves' stores
    if (tid == 0) st_flag(&dflags[b * 16], (unsigned)(2 * t + 1));
    // ---- a arrival ----
    wait_flags(dflags, (unsigned)(2 * t + 1), tid);
    if (tid < 128) {
      const unsigned ag = (unsigned)(t + 1);
      u64 p = ld_pk(&a_pk[tid]);
      while ((unsigned)(p >> 32) != ag) {
        __builtin_amdgcn_s_sleep(8);
        p = ld_pk(&a_pk[tid]);
      }
      af[tid] = __uint_as_float((unsigned)p);
    }
    __syncthreads();
    // softmax (per wave, from LDS)
    float ax = af[2 * l], ay = af[2 * l + 1];
    float mx = fmaxf(ax, ay);
#pragma unroll
    for (int off = 32; off; off >>= 1) mx = fmaxf(mx, __shfl_xor(mx, off));
    float pe0 = expf(ax - mx), pe1 = expf(ay - mx);
    float zs = pe0 + pe1;
#pragma unroll
    for (int off = 32; off; off >>= 1) zs += __shfl_xor(zs, off);
    float w0 = pe0 / zs, w1 = pe1 / zs;
    for (int s = w; s < 48; s += 4) {
      float2 g2 = *(const float2*)&Gl[s][2 * l];
      float acc = g2.x * w0 + g2.y * w1;
#pragma unroll
      for (int off = 32; off; off >>= 1) acc += __shfl_xor(acc, off);
      if (l == 0) giS[s] = acc + P1[(size_t)t * 3072 + grow_map(s, i0)];
    }
    __syncthreads();
    if (tid < 16) {
      int i = tid, ig = i0 + i;
      float gr = giS[i], gz = giS[16 + i], gn = giS[32 + i];
      float hr = ghl[i] + bh[i], hz = ghl[16 + i] + bh[16 + i], hn = ghl[32 + i] + bh[32 + i];
      float r = 1.f / (1.f + expf(-(gr + hr)));
      float z = 1.f / (1.f + expf(-(gz + hz)));
      float n = tanhf(gn + r * hn);
      float hpv = (1.f - z) * n + z * h_own[i];
      h_own[i] = hpv;
      Hs[(size_t)t * H_ + ig] = f2bf(hpv);
      float v0 = __shfl(hpv, (tid & 7) * 2);
      float v1 = __shfl(hpv, (tid & 7) * 2 + 1);
      if (tid < 8) {
        unsigned payload = (unsigned)f2bf(v0) | ((unsigned)f2bf(v1) << 16);
        pub_pk(&hx[((g + 1) & 1) * 512 + b * 8 + tid], g + 1, payload);
      }
    }
    __syncthreads();  // drains wave-0's h stores + protects LDS
    if (tid == 0) st_flag(&dflags[b * 16], (unsigned)(2 * t + 2));
  }
}

// ---------------- output GEMM ----------------
__global__ __launch_bounds__(256) void out_gemm(const unsigned short* __restrict__ A,
                                                const float* __restrict__ Wf,
                                                const float* __restrict__ bias,
                                                float* __restrict__ C, int N, int K) {
  __shared__ unsigned short As[256][40];
  __shared__ unsigned short Bs[64][40];
  const int bn = blockIdx.x * 64;
  const int tid = threadIdx.x, w = tid >> 6, l = tid & 63;
  f32x4 acc[4][4];
#pragma unroll
  for (int mf = 0; mf < 4; ++mf)
#pragma unroll
    for (int nf = 0; nf < 4; ++nf) acc[mf][nf] = (f32x4){0.f, 0.f, 0.f, 0.f};

  for (int k0 = 0; k0 < K; k0 += 32) {
    const unsigned short* src = A + (size_t)tid * K + k0;
#pragma unroll
    for (int kc = 0; kc < 4; ++kc) {
      short8 v = *(const short8*)(src + kc * 8);
      *(short8*)&As[tid][kc * 8] = v;
    }
#pragma unroll
    for (int c = 0; c < 2; ++c) {
      int idx = tid + c * 256;
      int n = idx >> 3, kc = idx & 7;
      int gn = bn + n;
      float4 v = {0.f, 0.f, 0.f, 0.f};
      if (gn < N) v = *(const float4*)&Wf[(size_t)gn * K + k0 + kc * 4];
      uint2 p;
      p.x = (unsigned)f2bf(v.x) | ((unsigned)f2bf(v.y) << 16);
      p.y = (unsigned)f2bf(v.z) | ((unsigned)f2bf(v.w) << 16);
      *(uint2*)&Bs[n][kc * 4] = p;
    }
    __syncthreads();
    const int k8 = (l >> 4) * 8;
    short8 af[4], bf[4];
#pragma unroll
    for (int mf = 0; mf < 4; ++mf) af[mf] = *(const short8*)&As[w * 64 + mf * 16 + (l & 15)][k8];
#pragma unroll
    for (int nf = 0; nf < 4; ++nf) bf[nf] = *(const short8*)&Bs[nf * 16 + (l & 15)][k8];
#pragma unroll
    for (int mf = 0; mf < 4; ++mf)
#pragma unroll
      for (int nf = 0; nf < 4; ++nf)
        acc[mf][nf] = __builtin_amdgcn_mfma_f32_16x16x32_bf16(af[mf], bf[nf], acc[mf][nf], 0, 0, 0);
    __syncthreads();
  }
#pragma unroll
  for (int mf = 0; mf < 4; ++mf) {
#pragma unroll
    for (int nf = 0; nf < 4; ++nf) {
      int n = bn + nf * 16 + (l & 15);
      if (n < N) {
        float bv = bias[n];
#pragma unroll
        for (int i = 0; i < 4; ++i) {
          int m = w * 64 + mf * 16 + (l >> 4) * 4 + i;
          C[(size_t)m * N + n] = acc[mf][nf][i] + bv;
        }
      }
    }
  }
}

// ---------------- log-softmax ----------------
__global__ __launch_bounds__(256) void lsm_stats(const float* __restrict__ C, float* __restrict__ stats, int N) {
  const int r = blockIdx.x, tid = threadIdx.x, w = tid >> 6, l = tid & 63;
  __shared__ float red[4];
  const float* row = C + (size_t)r * N;
  float m = -3.4e38f;
  for (int i = tid; i < N; i += 256) m = fmaxf(m, row[i]);
#pragma unroll
  for (int off = 32; off; off >>= 1) m = fmaxf(m, __shfl_xor(m, off));
  if (l == 0) red[w] = m;
  __syncthreads();
  m = fmaxf(fmaxf(red[0], red[1]), fmaxf(red[2], red[3]));
  __syncthreads();
  float s = 0.f;
  for (int i = tid; i < N; i += 256) s += expf(row[i] - m);
#pragma unroll
  for (int off = 32; off; off >>= 1) s += __shfl_xor(s, off);
  if (l == 0) red[w] = s;
  __syncthreads();
  if (tid == 0) {
    stats[r] = m;
    stats[256 + r] = logf(red[0] + red[1] + red[2] + red[3]);
  }
}

__global__ __launch_bounds__(256) void lsm_apply(float* __restrict__ C, const float* __restrict__ stats, int N) {
  int r = blockIdx.y;
  int ci = blockIdx.x * 256 + threadIdx.x;
  if (ci < N) {
    size_t idx = (size_t)r * N + ci;
    C[idx] = C[idx] - stats[r] - stats[256 + r];
  }
}

extern "C" void kernel_launch(void* const* d_in, const int* in_sizes, int n_in,
                              void* d_out, int out_size, void* d_ws, size_t ws_size,
                              hipStream_t stream) {
  (void)in_sizes; (void)n_in; (void)out_size; (void)ws_size;
  const int* motion = (const int*)d_in[0];
  const int* tgt = (const int*)d_in[1];
  const float* enc_emb = (const float*)d_in[2];
  const float* enc_Wih = (const float*)d_in[3];
  const float* enc_Whh = (const float*)d_in[4];
  const float* enc_bih = (const float*)d_in[5];
  const float* enc_bhh = (const float*)d_in[6];
  const float* dec_emb = (const float*)d_in[7];
  const float* dec_Wih = (const float*)d_in[8];
  const float* dec_Whh = (const float*)d_in[9];
  const float* dec_bih = (const float*)d_in[10];
  const float* dec_bhh = (const float*)d_in[11];
  const float* attn_W = (const float*)d_in[12];
  const float* attn_b = (const float*)d_in[13];
  const float* comb_W = (const float*)d_in[14];
  const float* comb_b = (const float*)d_in[15];
  const float* out_W = (const float*)d_in[16];
  const float* out_b = (const float*)d_in[17];
  float* out = (float*)d_out;

  // workspace layout (floats, 16B-aligned chunks)
  float* wsf = (float*)d_ws;
  size_t o = 0;
  auto F = [&](size_t n) { float* p = wsf + o; o += (n + 3) & ~(size_t)3; return p; };
  float* enc_gi = F(128 * 3072);
  float* enc_outs = F(128 * 1024);
  float* embA = F(128 * 512);
  float* demb = F(256 * 1024);
  float* aE = F(256 * 128);
  float* xE = F(256 * 1024);
  float* P1 = F(256 * 3072);
  float* M2T = F(128 * 1024);
  float* Gm = F(3072 * 128);
  u64* hx = (u64*)F(2048);         // [2][512] packed {gen, 2xbf16}       (8 KB)
  u64* a_pk = (u64*)F(256);        // [128] packed {gen, f32}             (1 KB)
  unsigned* eflags = (unsigned*)F(1024);  // 64 flags, 64B apart          (4 KB)
  unsigned* dflags = (unsigned*)F(1024);  // 64 flags, 64B apart          (4 KB)
  float* stats = F(512);
  unsigned short* Hs = (unsigned short*)F(256 * 1024 / 2);

  // fresh gens/flags each launch (graph-replay determinism); hx..dflags contiguous
  hipMemsetAsync(hx, 0, (2048 + 256 + 1024 + 1024) * sizeof(float), stream);

  // batched precompute
  gather_enc<<<128, 128, 0, stream>>>(motion, enc_emb, embA);
  gemm_f32<<<dim3(48, 2), 256, 0, stream>>>(embA, 512, enc_Wih, 512, enc_bih, enc_gi, 3072, 512);
  gather_dec<<<256, 256, 0, stream>>>(tgt, dec_emb, demb);
  gemm_f32<<<dim3(2, 4), 256, 0, stream>>>(demb, 1024, attn_W, 2048, attn_b, aE, 128, 1024);
  gemm_f32<<<dim3(16, 4), 256, 0, stream>>>(demb, 1024, comb_W, 2048, comb_b, xE, 1024, 1024);
  gemm_f32<<<dim3(48, 4), 256, 0, stream>>>(xE, 1024, dec_Wih, 1024, dec_bih, P1, 3072, 1024);

  // encoder recurrence (flag-gated)
  enc_rnn<<<NBLK, 256, 0, stream>>>(enc_Whh, enc_bhh, enc_gi, hx, eflags, enc_outs);

  // G = dec_Wih @ (comb_W[:,H:] @ enc_outs^T)
  gemm_f32<<<dim3(16, 2), 256, 0, stream>>>(enc_outs, 1024, comb_W + 1024, 2048, nullptr, M2T, 1024, 1024);
  gemm_f32<<<dim3(2, 48), 256, 0, stream>>>(dec_Wih, 1024, M2T, 1024, nullptr, Gm, 128, 1024);

  // decoder recurrence (flag-gated)
  dec_rnn<<<NBLK, 256, 0, stream>>>(dec_Whh, dec_bhh, attn_W, Gm, P1, aE,
                                    enc_outs + (size_t)(LM_ - 1) * H_, a_pk, hx, dflags, Hs);

  // output projection + log-softmax
  out_gemm<<<786, 256, 0, stream>>>(Hs, out_W, out_b, out, V_, 1024);
  lsm_stats<<<256, 256, 0, stream>>>(out, stats, V_);
  lsm_apply<<<dim3(197, 256), 256, 0, stream>>>(out, stats, V_);
}

// Round 5
// 4361.536 us; speedup vs baseline: 1.1613x; 1.1613x over previous
//
#include <hip/hip_runtime.h>

// Problem dims
#define V_ 50257
#define E_ 512
#define H_ 1024
#define LM_ 128
#define LC_ 256
#define NBLK 64   // blocks in persistent recurrence kernels

typedef __attribute__((ext_vector_type(8))) short short8;
typedef __attribute__((ext_vector_type(4))) float f32x4;
typedef unsigned long long u64;

__device__ __forceinline__ unsigned short f2bf(float x) {
  union { float f; unsigned u; } v; v.f = x;
  unsigned r = v.u + 0x7fffu + ((v.u >> 16) & 1u);   // round-to-nearest-even
  return (unsigned short)(r >> 16);
}
__device__ __forceinline__ float bflo(unsigned u) { union { unsigned u; float f; } v; v.u = u << 16; return v.f; }
__device__ __forceinline__ float bfhi(unsigned u) { union { unsigned u; float f; } v; v.u = u & 0xffff0000u; return v.f; }

__device__ __forceinline__ int grow_map(int s, int i0) {
  return (s < 16) ? (i0 + s) : (s < 32) ? (1024 + i0 + (s - 16)) : (2048 + i0 + (s - 32));
}

// relaxed agent-scope ops (uncached at coherence point; no fences -> no L2 flush/inv)
__device__ __forceinline__ void st_u32(unsigned* p, unsigned v) {
  __hip_atomic_store(p, v, __ATOMIC_RELAXED, __HIP_MEMORY_SCOPE_AGENT);
}
__device__ __forceinline__ u64 ld_u64(const u64* p) {
  return __hip_atomic_load(p, __ATOMIC_RELAXED, __HIP_MEMORY_SCOPE_AGENT);
}
__device__ __forceinline__ unsigned ld_flag(const unsigned* p) {
  return __hip_atomic_load(p, __ATOMIC_RELAXED, __HIP_MEMORY_SCOPE_AGENT);
}

// wave-0 flag wait: lane b polls publisher b's flag line until all >= need.
__device__ __forceinline__ void wait_flags(const unsigned* flags, unsigned need, int tid) {
  if (tid < 64) {
    for (;;) {
      unsigned f = ld_flag(&flags[tid * 16]);
      if (__all(f >= need)) break;
      __builtin_amdgcn_s_sleep(2);
    }
  }
  __syncthreads();
}

// ---------------- gathers ----------------
__global__ void gather_enc(const int* __restrict__ motion, const float* __restrict__ emb,
                           float* __restrict__ dst) {
  int t = blockIdx.x;
  int tok = motion[t];
  const float4* s = (const float4*)(emb + (size_t)tok * E_);
  float4* d = (float4*)(dst + (size_t)t * E_);
  d[threadIdx.x] = s[threadIdx.x];
}

__global__ void gather_dec(const int* __restrict__ tgt, const float* __restrict__ emb,
                           float* __restrict__ dst) {
  int t = blockIdx.x;
  int tok = (t == 0) ? 0 : (t == 1 ? tgt[LC_ - 1] : tgt[t - 2]);
  const float4* s = (const float4*)(emb + (size_t)tok * H_);
  float4* d = (float4*)(dst + (size_t)t * H_);
  d[threadIdx.x] = s[threadIdx.x];
}

// ---------------- generic f32 GEMM: C[M,N] = A[M,K](lda) @ B[N,K](ldb)^T + bias ----------------
__global__ __launch_bounds__(256) void gemm_f32(const float* __restrict__ A, int lda,
                                                const float* __restrict__ B, int ldb,
                                                const float* __restrict__ bias,
                                                float* __restrict__ C, int ldc, int K) {
  __shared__ float As[16][68];
  __shared__ float Bs[16][68];
  const int bm = blockIdx.y * 64, bn = blockIdx.x * 64;
  const int tid = threadIdx.x;
  const int tx = tid & 15, ty = tid >> 4;
  const int lm = tid & 63, lk = (tid >> 6) * 4;
  float acc[4][4] = {};
  for (int k0 = 0; k0 < K; k0 += 16) {
    float4 av = *(const float4*)&A[(size_t)(bm + lm) * lda + k0 + lk];
    float4 bv = *(const float4*)&B[(size_t)(bn + lm) * ldb + k0 + lk];
    As[lk + 0][lm] = av.x; As[lk + 1][lm] = av.y; As[lk + 2][lm] = av.z; As[lk + 3][lm] = av.w;
    Bs[lk + 0][lm] = bv.x; Bs[lk + 1][lm] = bv.y; Bs[lk + 2][lm] = bv.z; Bs[lk + 3][lm] = bv.w;
    __syncthreads();
#pragma unroll
    for (int kk = 0; kk < 16; ++kk) {
      float4 a4 = *(const float4*)&As[kk][ty * 4];
      float4 b4 = *(const float4*)&Bs[kk][tx * 4];
      acc[0][0] += a4.x * b4.x; acc[0][1] += a4.x * b4.y; acc[0][2] += a4.x * b4.z; acc[0][3] += a4.x * b4.w;
      acc[1][0] += a4.y * b4.x; acc[1][1] += a4.y * b4.y; acc[1][2] += a4.y * b4.z; acc[1][3] += a4.y * b4.w;
      acc[2][0] += a4.z * b4.x; acc[2][1] += a4.z * b4.y; acc[2][2] += a4.z * b4.z; acc[2][3] += a4.z * b4.w;
      acc[3][0] += a4.w * b4.x; acc[3][1] += a4.w * b4.y; acc[3][2] += a4.w * b4.z; acc[3][3] += a4.w * b4.w;
    }
    __syncthreads();
  }
#pragma unroll
  for (int i = 0; i < 4; ++i) {
#pragma unroll
    for (int j = 0; j < 4; ++j) {
      int gm = bm + ty * 4 + i, gn = bn + tx * 4 + j;
      float bv = bias ? bias[gn] : 0.f;
      C[(size_t)gm * ldc + gn] = acc[i][j] + bv;
    }
  }
}

// ---------------- encoder recurrence: column-partial, 1 hop/step ----------------
// Block b holds Whh[:, b*16:(b+1)*16] (bf16, u-plane layout). Per step:
// partials = Wcols * h_own (local) -> publish 3072 f32 -> flag -> wait -> read own 48
// rows x 64 partials -> reduce -> gates -> h_own.
__global__ __launch_bounds__(256) void enc_rnn(const float* __restrict__ Whh,
                                               const float* __restrict__ bhh,
                                               const float* __restrict__ gi,
                                               float* __restrict__ gpart,
                                               unsigned* __restrict__ eflags,
                                               float* __restrict__ outs) {
  __shared__ unsigned Wc[8 * 3072];   // 96 KB, plane u: Wc[u*3072+r] = {W[r][i0+2u], W[r][i0+2u+1]}
  __shared__ float gpl[48][66];       // staged partials [s][b']
  __shared__ float red4[48][4];
  __shared__ float h_own[16];
  __shared__ float bh[48];
  const int b = blockIdx.x, tid = threadIdx.x;
  const int i0 = b * 16;
  for (int m = 0; m < 96; ++m) {
    int idx = tid + 256 * m;                 // 24576
    int u = idx / 3072, r = idx - u * 3072;
    float2 wv = *(const float2*)&Whh[(size_t)r * H_ + i0 + 2 * u];
    Wc[idx] = (unsigned)f2bf(wv.x) | ((unsigned)f2bf(wv.y) << 16);
  }
  if (tid < 48) bh[tid] = bhh[grow_map(tid, i0)];
  if (tid < 16) h_own[tid] = 0.f;
  __syncthreads();

  for (int t = 0; t < LM_; ++t) {
    // 1. local partials from h_t
    float hh[16];
#pragma unroll
    for (int j = 0; j < 16; ++j) hh[j] = h_own[j];
    float* gslot = gpart + (size_t)(t & 1) * (NBLK * 3072) + (size_t)b * 3072;
#pragma unroll
    for (int k = 0; k < 12; ++k) {
      int r = tid + 256 * k;
      float acc = 0.f;
#pragma unroll
      for (int u = 0; u < 8; ++u) {
        unsigned wv = Wc[u * 3072 + r];
        acc += bflo(wv) * hh[2 * u] + bfhi(wv) * hh[2 * u + 1];
      }
      st_u32((unsigned*)&gslot[r], __float_as_uint(acc));
    }
    __syncthreads();  // drains the partial stores (vmcnt0 before barrier)
    if (tid == 0) st_u32(&eflags[b * 16], (unsigned)(t + 1));
    wait_flags(eflags, (unsigned)(t + 1), tid);

    // 2. burst-read own 48 rows x 64 partials (6 u64/thread)
    const u64* gbase = (const u64*)(gpart + (size_t)(t & 1) * (NBLK * 3072));
#pragma unroll
    for (int m = 0; m < 6; ++m) {
      int idx = tid + 256 * m;                // 0..1535
      int u = idx & 7, c = (idx >> 3) % 3, bp = idx / 24;
      u64 v = ld_u64(gbase + (size_t)bp * 1536 + (c * 1024 + i0) / 2 + u);
      int s = c * 16 + 2 * u;
      gpl[s][bp] = __uint_as_float((unsigned)v);
      gpl[s + 1][bp] = __uint_as_float((unsigned)(v >> 32));
    }
    __syncthreads();
    // 3. reduce
    if (tid < 192) {
      int s = tid >> 2, q = tid & 3;
      float p = 0.f;
#pragma unroll
      for (int j = 0; j < 16; ++j) p += gpl[s][q * 16 + j];
      red4[s][q] = p;
    }
    __syncthreads();
    // 4. gates
    if (tid < 16) {
      int i = tid, ig = i0 + i;
      const float* git = gi + (size_t)t * 3072;
      float s0[3];
#pragma unroll
      for (int c = 0; c < 3; ++c) {
        int s = c * 16 + i;
        s0[c] = red4[s][0] + red4[s][1] + red4[s][2] + red4[s][3] + bh[s];
      }
      float gr = git[ig], gz = git[1024 + ig], gn = git[2048 + ig];
      float r = 1.f / (1.f + expf(-(gr + s0[0])));
      float z = 1.f / (1.f + expf(-(gz + s0[1])));
      float n = tanhf(gn + r * s0[2]);
      float hpv = (1.f - z) * n + z * h_own[i];
      h_own[i] = hpv;
      outs[(size_t)t * H_ + ig] = hpv;
    }
    __syncthreads();
  }
}

// ---------------- decoder recurrence: column-partial, 1 hop/step ----------------
// Block b holds dec_Whh[:,chunk] (96 KB) and A_h[:,chunk] (4 KB). Per step: gh- and
// a-partials local from h_own -> single publish+flag -> wait -> read 48x64 gh-partials
// + all 64x128 bf16 a-partials -> reduce -> softmax local -> G.w local -> gates.
__global__ __launch_bounds__(256) void dec_rnn(const float* __restrict__ Whh,
                                               const float* __restrict__ bhh,
                                               const float* __restrict__ attn_W,
                                               const float* __restrict__ G,
                                               const float* __restrict__ P1,
                                               const float* __restrict__ aE,
                                               const float* __restrict__ hfin,
                                               float* __restrict__ gpart,
                                               unsigned* __restrict__ apart,
                                               unsigned* __restrict__ dflags,
                                               unsigned short* __restrict__ Hs) {
  __shared__ unsigned Wc[8 * 3072];   // 96 KB
  __shared__ unsigned Ac[8 * 128];    // 4 KB, plane u: Ac[u*128+j]
  __shared__ float Gl[48][128];       // 24 KB
  __shared__ float gpl[48][66];       // 12.4 KB
  __shared__ unsigned apl[64 * 64];   // 16 KB  [bp*64 + jp]
  __shared__ float red4[48][4];
  __shared__ float a_f[128];
  __shared__ float h_own[16];
  __shared__ float bh[48];
  __shared__ float giS[48];
  const int b = blockIdx.x, tid = threadIdx.x;
  const int w = tid >> 6, l = tid & 63;
  const int i0 = b * 16;
  for (int m = 0; m < 96; ++m) {
    int idx = tid + 256 * m;
    int u = idx / 3072, r = idx - u * 3072;
    float2 wv = *(const float2*)&Whh[(size_t)r * H_ + i0 + 2 * u];
    Wc[idx] = (unsigned)f2bf(wv.x) | ((unsigned)f2bf(wv.y) << 16);
  }
  for (int m = 0; m < 4; ++m) {
    int idx = tid + 256 * m;                 // 1024
    int u = idx >> 7, j = idx & 127;
    float2 wv = *(const float2*)&attn_W[(size_t)j * 2048 + 1024 + i0 + 2 * u];
    Ac[idx] = (unsigned)f2bf(wv.x) | ((unsigned)f2bf(wv.y) << 16);
  }
  for (int idx = tid; idx < 48 * 128; idx += 256) {
    int s = idx >> 7, c = idx & 127;
    Gl[s][c] = G[(size_t)grow_map(s, i0) * 128 + c];
  }
  if (tid < 48) bh[tid] = bhh[grow_map(tid, i0)];
  if (tid < 16) h_own[tid] = hfin[i0 + tid];   // exact f32 encoder-final h
  __syncthreads();

  for (int t = 0; t < LC_; ++t) {
    // 1. local partials from h_t
    float hh[16];
#pragma unroll
    for (int j = 0; j < 16; ++j) hh[j] = h_own[j];
    float* gslot = gpart + (size_t)(t & 1) * (NBLK * 3072) + (size_t)b * 3072;
#pragma unroll
    for (int k = 0; k < 12; ++k) {
      int r = tid + 256 * k;
      float acc = 0.f;
#pragma unroll
      for (int u = 0; u < 8; ++u) {
        unsigned wv = Wc[u * 3072 + r];
        acc += bflo(wv) * hh[2 * u] + bfhi(wv) * hh[2 * u + 1];
      }
      st_u32((unsigned*)&gslot[r], __float_as_uint(acc));
    }
    if (tid < 64) {   // a-partials: rows 2*tid, 2*tid+1
      float a0 = 0.f, a1 = 0.f;
#pragma unroll
      for (int u = 0; u < 8; ++u) {
        unsigned w0 = Ac[u * 128 + 2 * tid];
        unsigned w1 = Ac[u * 128 + 2 * tid + 1];
        a0 += bflo(w0) * hh[2 * u] + bfhi(w0) * hh[2 * u + 1];
        a1 += bflo(w1) * hh[2 * u] + bfhi(w1) * hh[2 * u + 1];
      }
      unsigned pk = (unsigned)f2bf(a0) | ((unsigned)f2bf(a1) << 16);
      st_u32(&apart[(t & 1) * (NBLK * 64) + b * 64 + tid], pk);
    }
    __syncthreads();  // drain all publish stores
    if (tid == 0) st_u32(&dflags[b * 16], (unsigned)(t + 1));
    wait_flags(dflags, (unsigned)(t + 1), tid);

    // 2. burst reads
    const u64* gbase = (const u64*)(gpart + (size_t)(t & 1) * (NBLK * 3072));
#pragma unroll
    for (int m = 0; m < 6; ++m) {
      int idx = tid + 256 * m;
      int u = idx & 7, c = (idx >> 3) % 3, bp = idx / 24;
      u64 v = ld_u64(gbase + (size_t)bp * 1536 + (c * 1024 + i0) / 2 + u);
      int s = c * 16 + 2 * u;
      gpl[s][bp] = __uint_as_float((unsigned)v);
      gpl[s + 1][bp] = __uint_as_float((unsigned)(v >> 32));
    }
    const u64* abase = (const u64*)(apart + (t & 1) * (NBLK * 64));
#pragma unroll
    for (int m = 0; m < 4; ++m) {
      int idx = tid + 256 * m;                // 0..1023 u64
      u64 v = ld_u64(abase + idx);
      apl[2 * idx] = (unsigned)v;
      apl[2 * idx + 1] = (unsigned)(v >> 32);
    }
    __syncthreads();

    // 3a. a-reduce: 2 threads per entry j (32 terms each), combine via shfl
    {
      int j = tid >> 1, shalf = tid & 1, jp = j >> 1, hi = j & 1;
      float pa = 0.f;
#pragma unroll
      for (int q = 0; q < 32; ++q) {
        unsigned wv = apl[(32 * shalf + q) * 64 + jp];
        pa += hi ? bfhi(wv) : bflo(wv);
      }
      pa += __shfl_xor(pa, 1);
      if (!shalf) a_f[j] = pa + aE[(size_t)t * LM_ + j];
    }
    // 3b. gh-partial reduce
    if (tid < 192) {
      int s = tid >> 2, q = tid & 3;
      float p = 0.f;
#pragma unroll
      for (int j = 0; j < 16; ++j) p += gpl[s][q * 16 + j];
      red4[s][q] = p;
    }
    __syncthreads();

    // 4. softmax over a[128] (per-wave redundant, from LDS)
    float ax = a_f[2 * l], ay = a_f[2 * l + 1];
    float mx = fmaxf(ax, ay);
#pragma unroll
    for (int off = 32; off; off >>= 1) mx = fmaxf(mx, __shfl_xor(mx, off));
    float pe0 = expf(ax - mx), pe1 = expf(ay - mx);
    float zs = pe0 + pe1;
#pragma unroll
    for (int off = 32; off; off >>= 1) zs += __shfl_xor(zs, off);
    float w0 = pe0 / zs, w1 = pe1 / zs;
    // 5. gi = P1 + G.w
    for (int s = w; s < 48; s += 4) {
      float2 g2 = *(const float2*)&Gl[s][2 * l];
      float acc = g2.x * w0 + g2.y * w1;
#pragma unroll
      for (int off = 32; off; off >>= 1) acc += __shfl_xor(acc, off);
      if (l == 0) giS[s] = acc + P1[(size_t)t * 3072 + grow_map(s, i0)];
    }
    __syncthreads();
    // 6. gates
    if (tid < 16) {
      int i = tid, ig = i0 + i;
      float s0[3];
#pragma unroll
      for (int c = 0; c < 3; ++c) {
        int s = c * 16 + i;
        s0[c] = red4[s][0] + red4[s][1] + red4[s][2] + red4[s][3] + bh[s];
      }
      float r = 1.f / (1.f + expf(-(giS[i] + s0[0])));
      float z = 1.f / (1.f + expf(-(giS[16 + i] + s0[1])));
      float n = tanhf(giS[32 + i] + r * s0[2]);
      float hpv = (1.f - z) * n + z * h_own[i];
      h_own[i] = hpv;
      Hs[(size_t)t * H_ + ig] = f2bf(hpv);
    }
    __syncthreads();
  }
}

// ---------------- output GEMM ----------------
__global__ __launch_bounds__(256) void out_gemm(const unsigned short* __restrict__ A,
                                                const float* __restrict__ Wf,
                                                const float* __restrict__ bias,
                                                float* __restrict__ C, int N, int K) {
  __shared__ unsigned short As[256][40];
  __shared__ unsigned short Bs[64][40];
  const int bn = blockIdx.x * 64;
  const int tid = threadIdx.x, w = tid >> 6, l = tid & 63;
  f32x4 acc[4][4];
#pragma unroll
  for (int mf = 0; mf < 4; ++mf)
#pragma unroll
    for (int nf = 0; nf < 4; ++nf) acc[mf][nf] = (f32x4){0.f, 0.f, 0.f, 0.f};

  for (int k0 = 0; k0 < K; k0 += 32) {
    const unsigned short* src = A + (size_t)tid * K + k0;
#pragma unroll
    for (int kc = 0; kc < 4; ++kc) {
      short8 v = *(const short8*)(src + kc * 8);
      *(short8*)&As[tid][kc * 8] = v;
    }
#pragma unroll
    for (int c = 0; c < 2; ++c) {
      int idx = tid + c * 256;
      int n = idx >> 3, kc = idx & 7;
      int gn = bn + n;
      float4 v = {0.f, 0.f, 0.f, 0.f};
      if (gn < N) v = *(const float4*)&Wf[(size_t)gn * K + k0 + kc * 4];
      uint2 p;
      p.x = (unsigned)f2bf(v.x) | ((unsigned)f2bf(v.y) << 16);
      p.y = (unsigned)f2bf(v.z) | ((unsigned)f2bf(v.w) << 16);
      *(uint2*)&Bs[n][kc * 4] = p;
    }
    __syncthreads();
    const int k8 = (l >> 4) * 8;
    short8 af4[4], bf4[4];
#pragma unroll
    for (int mf = 0; mf < 4; ++mf) af4[mf] = *(const short8*)&As[w * 64 + mf * 16 + (l & 15)][k8];
#pragma unroll
    for (int nf = 0; nf < 4; ++nf) bf4[nf] = *(const short8*)&Bs[nf * 16 + (l & 15)][k8];
#pragma unroll
    for (int mf = 0; mf < 4; ++mf)
#pragma unroll
      for (int nf = 0; nf < 4; ++nf)
        acc[mf][nf] = __builtin_amdgcn_mfma_f32_16x16x32_bf16(af4[mf], bf4[nf], acc[mf][nf], 0, 0, 0);
    __syncthreads();
  }
#pragma unroll
  for (int mf = 0; mf < 4; ++mf) {
#pragma unroll
    for (int nf = 0; nf < 4; ++nf) {
      int n = bn + nf * 16 + (l & 15);
      if (n < N) {
        float bv = bias[n];
#pragma unroll
        for (int i = 0; i < 4; ++i) {
          int m = w * 64 + mf * 16 + (l >> 4) * 4 + i;
          C[(size_t)m * N + n] = acc[mf][nf][i] + bv;
        }
      }
    }
  }
}

// ---------------- log-softmax ----------------
__global__ __launch_bounds__(256) void lsm_stats(const float* __restrict__ C, float* __restrict__ stats, int N) {
  const int r = blockIdx.x, tid = threadIdx.x, w = tid >> 6, l = tid & 63;
  __shared__ float red[4];
  const float* row = C + (size_t)r * N;
  float m = -3.4e38f;
  for (int i = tid; i < N; i += 256) m = fmaxf(m, row[i]);
#pragma unroll
  for (int off = 32; off; off >>= 1) m = fmaxf(m, __shfl_xor(m, off));
  if (l == 0) red[w] = m;
  __syncthreads();
  m = fmaxf(fmaxf(red[0], red[1]), fmaxf(red[2], red[3]));
  __syncthreads();
  float s = 0.f;
  for (int i = tid; i < N; i += 256) s += expf(row[i] - m);
#pragma unroll
  for (int off = 32; off; off >>= 1) s += __shfl_xor(s, off);
  if (l == 0) red[w] = s;
  __syncthreads();
  if (tid == 0) {
    stats[r] = m;
    stats[256 + r] = logf(red[0] + red[1] + red[2] + red[3]);
  }
}

__global__ __launch_bounds__(256) void lsm_apply(float* __restrict__ C, const float* __restrict__ stats, int N) {
  int r = blockIdx.y;
  int ci = blockIdx.x * 256 + threadIdx.x;
  if (ci < N) {
    size_t idx = (size_t)r * N + ci;
    C[idx] = C[idx] - stats[r] - stats[256 + r];
  }
}

extern "C" void kernel_launch(void* const* d_in, const int* in_sizes, int n_in,
                              void* d_out, int out_size, void* d_ws, size_t ws_size,
                              hipStream_t stream) {
  (void)in_sizes; (void)n_in; (void)out_size; (void)ws_size;
  const int* motion = (const int*)d_in[0];
  const int* tgt = (const int*)d_in[1];
  const float* enc_emb = (const float*)d_in[2];
  const float* enc_Wih = (const float*)d_in[3];
  const float* enc_Whh = (const float*)d_in[4];
  const float* enc_bih = (const float*)d_in[5];
  const float* enc_bhh = (const float*)d_in[6];
  const float* dec_emb = (const float*)d_in[7];
  const float* dec_Wih = (const float*)d_in[8];
  const float* dec_Whh = (const float*)d_in[9];
  const float* dec_bih = (const float*)d_in[10];
  const float* dec_bhh = (const float*)d_in[11];
  const float* attn_W = (const float*)d_in[12];
  const float* attn_b = (const float*)d_in[13];
  const float* comb_W = (const float*)d_in[14];
  const float* comb_b = (const float*)d_in[15];
  const float* out_W = (const float*)d_in[16];
  const float* out_b = (const float*)d_in[17];
  float* out = (float*)d_out;

  // workspace layout (floats, 16B-aligned chunks)
  float* wsf = (float*)d_ws;
  size_t o = 0;
  auto F = [&](size_t n) { float* p = wsf + o; o += (n + 3) & ~(size_t)3; return p; };
  float* enc_gi = F(128 * 3072);
  float* enc_outs = F(128 * 1024);
  float* embA = F(128 * 512);
  float* demb = F(256 * 1024);
  float* aE = F(256 * 128);
  float* xE = F(256 * 1024);
  float* P1 = F(256 * 3072);
  float* M2T = F(128 * 1024);
  float* Gm = F(3072 * 128);
  float* gpart = F(2 * NBLK * 3072);          // partial gh, double-slot (1.5 MB)
  unsigned* apart = (unsigned*)F(2 * NBLK * 64);  // packed bf16 a-partials
  unsigned* eflags = (unsigned*)F(1024);      // 64 flags, 64B apart
  unsigned* dflags = (unsigned*)F(1024);
  float* stats = F(512);
  unsigned short* Hs = (unsigned short*)F(256 * 1024 / 2);

  // fresh flags each launch (graph-replay determinism); eflags+dflags contiguous
  hipMemsetAsync(eflags, 0, 2048 * sizeof(float), stream);

  // batched precompute
  gather_enc<<<128, 128, 0, stream>>>(motion, enc_emb, embA);
  gemm_f32<<<dim3(48, 2), 256, 0, stream>>>(embA, 512, enc_Wih, 512, enc_bih, enc_gi, 3072, 512);
  gather_dec<<<256, 256, 0, stream>>>(tgt, dec_emb, demb);
  gemm_f32<<<dim3(2, 4), 256, 0, stream>>>(demb, 1024, attn_W, 2048, attn_b, aE, 128, 1024);
  gemm_f32<<<dim3(16, 4), 256, 0, stream>>>(demb, 1024, comb_W, 2048, comb_b, xE, 1024, 1024);
  gemm_f32<<<dim3(48, 4), 256, 0, stream>>>(xE, 1024, dec_Wih, 1024, dec_bih, P1, 3072, 1024);

  // encoder recurrence (column-partial, 1 hop/step)
  enc_rnn<<<NBLK, 256, 0, stream>>>(enc_Whh, enc_bhh, enc_gi, gpart, eflags, enc_outs);

  // G = dec_Wih @ (comb_W[:,H:] @ enc_outs^T)
  gemm_f32<<<dim3(16, 2), 256, 0, stream>>>(enc_outs, 1024, comb_W + 1024, 2048, nullptr, M2T, 1024, 1024);
  gemm_f32<<<dim3(2, 48), 256, 0, stream>>>(dec_Wih, 1024, M2T, 1024, nullptr, Gm, 128, 1024);

  // decoder recurrence (column-partial, 1 hop/step)
  dec_rnn<<<NBLK, 256, 0, stream>>>(dec_Whh, dec_bhh, attn_W, Gm, P1, aE,
                                    enc_outs + (size_t)(LM_ - 1) * H_, gpart, apart, dflags, Hs);

  // output projection + log-softmax
  out_gemm<<<786, 256, 0, stream>>>(Hs, out_W, out_b, out, V_, 1024);
  lsm_stats<<<256, 256, 0, stream>>>(out, stats, V_);
  lsm_apply<<<dim3(197, 256), 256, 0, stream>>>(out, stats, V_);
}